// Round 13
// baseline (117.758 us; speedup 1.0000x reference)
//
#include <hip/hip_runtime.h>

// Simple_TensorProduct (e3nn uvw TP, MUL=256, l<=1, v=1) as two fused bf16 GEMMs.
//   out0[z,w]      = sum_k T0[z,k]    * B0[k,w]   (K=512)
//   out1[(z,c),w]  = sum_k T1[(z,c),k]* B1[k,w]   (K=768, M=3N)
//
// R13: occupancy + VALU-overhead attack on the R12 zero-barrier design.
//  - 1-WAVE blocks (64 thr): wave = 16 z-rows x 32 cols (ct=2), grid 10000.
//    Wave-private LDS 11.25 KB/block -> 14 blocks/CU LDS-cap; bounds(64,3)
//    -> 12 drifting waves/CU (2x R12's occupancy). No barriers anywhere.
//  - v_cvt_pk_bf16_f32 replaces 6-op manual RNE pack (~2.5x build-VALU cut).
//  - R10-proven per-wave asm pipeline: burstB(+10) -> vmcnt(10)=x1 done ->
//    build -> issue x1(c+1) -> vmcnt(8)=B done -> gemm. u-chunk 32, kt==seg.

typedef short bf16x8 __attribute__((ext_vector_type(8)));
typedef float f32x4 __attribute__((ext_vector_type(4)));
typedef int   ni4   __attribute__((ext_vector_type(4)));

static __device__ __forceinline__ unsigned short f2bf(float f) {
  unsigned int u = __builtin_bit_cast(unsigned int, f);
  u += 0x7FFFu + ((u >> 16) & 1u);   // RNE (prep kernel only)
  return (unsigned short)(u >> 16);
}

// 2x f32 -> packed bf16x2, RNE, single instruction. lo -> D[15:0].
static __device__ __forceinline__ int cvtpk(float lo, float hi) {
  int r;
  asm("v_cvt_pk_bf16_f32 %0, %1, %2" : "=v"(r) : "v"(lo), "v"(hi));
  return r;
}

static __device__ __forceinline__ bf16x8 asbf(int4 v) {
  return __builtin_bit_cast(bf16x8, v);
}
static __device__ __forceinline__ bf16x8 asbfn(ni4 v) {
  return __builtin_bit_cast(bf16x8, v);
}

static __device__ __forceinline__ void gload4(ni4& dst, const void* p) {
  asm volatile("global_load_dwordx4 %0, %1, off" : "=v"(dst) : "v"(p));
}

#define WAITV(n) do { \
    asm volatile("s_waitcnt vmcnt(" #n ")"); \
    __builtin_amdgcn_sched_barrier(0); \
  } while (0)

// ---------------------------------------------------------------------------
// Weight prep (verbatim R12, passed): u-chunk = 32, c in 0..7, kt==seg.
// B1: fid = ((c*3+kt)*16+ct)*64+lane; elem e: kc=kt*32+(lane>>4)*8+e (0..95),
//     seg=kc>>5, u=c*32+(kc&31), w=ct*16+(lane&15)
// B0: fid = 24576 + ((c*2+kt)*16+ct)*64+lane; kc 0..63, seg=kc>>5
// ---------------------------------------------------------------------------
__global__ __launch_bounds__(256) void prep_weights(
    const float* __restrict__ wgt, unsigned short* __restrict__ Bw)
{
  int fid = blockIdx.x * 256 + threadIdx.x;
  union { unsigned short h[8]; int4 v; } pk;
  if (fid < 24576) {
    int lane = fid & 63;
    int ct = (fid >> 6) & 15;
    int q = fid >> 10;            // 0..23 = c*3 + kt
    int kt = q % 3, c = q / 3;
    int w = ct * 16 + (lane & 15);
    int kh = (lane >> 4) * 8;
#pragma unroll
    for (int e = 0; e < 8; ++e) {
      int kc = kt * 32 + kh + e;       // 0..95
      int seg = kc >> 5;
      int u = c * 32 + (kc & 31);
      float s  = (seg == 2) ? 0.025515518153991442f : 0.03608439182435161f;
      int off  = (seg == 0) ? 65536 : (seg == 1 ? 131072 : 262144);
      pk.h[e] = f2bf(wgt[off + u * 256 + w] * s);
    }
    ((int4*)Bw)[fid] = pk.v;
  } else if (fid < 40960) {
    int f2 = fid - 24576;
    int lane = f2 & 63;
    int ct = (f2 >> 6) & 15;
    int q = f2 >> 10;             // 0..15 = c*2 + kt
    int kt = q & 1, c = q >> 1;
    int w = ct * 16 + (lane & 15);
    int kh = (lane >> 4) * 8;
#pragma unroll
    for (int e = 0; e < 8; ++e) {
      int kc = kt * 32 + kh + e;       // 0..63
      int seg = kc >> 5;
      int u = c * 32 + (kc & 31);
      float s  = (seg == 0) ? 0.04419417382415922f : 0.025515518153991442f;
      int off  = (seg == 0) ? 0 : 196608;
      pk.h[e] = f2bf(wgt[off + u * 256 + w] * s);
    }
    ((int4*)Bw)[fid] = pk.v;
  }
}

// Per-wave LDS map (int4 slots, 704 = 11.25 KB):
//   T1: rt*192 + kt*64 + fl   (rt 0..2, kt 0..2)
//   T0: 576 + kt*64 + fl      (kt 0..1)
#define T0BASE 576

struct X1Raw { ni4 a[8]; };   // s1[8] (2 regs) + v1[8u x 3k] (6 regs), raw bits

static __device__ __forceinline__ void load_x1_asm(
    X1Raw& r, const float* __restrict__ x1, int zrow, int ub, int rr)
{
  const float* base = x1 + (size_t)zrow * 1024;
  const float* ps = base + ub + rr * 8;
  gload4(r.a[0], ps);
  gload4(r.a[1], ps + 4);
  const float* pv = base + 256 + 3 * ub + rr * 24;
#pragma unroll
  for (int i = 0; i < 6; ++i) gload4(r.a[2 + i], pv + 4 * i);
}

// thread (zl = lane>>2, rr = lane&3) owns u-run [rr*8, rr*8+8) of the 32-u
// chunk. kt = sg; fragment lane fl = ((rr<<4)|(row&15)) ^ kt ^ rr.
// (verbatim R12 math; packing now via v_cvt_pk_bf16_f32)
static __device__ __forceinline__ void build_frags(
    const X1Raw& r, int zl, int rr, float s2, const float* v2, int4* wbuf)
{
  union { float4 q[2]; float f[8]; } s1u;
  s1u.q[0] = __builtin_bit_cast(float4, r.a[0]);
  s1u.q[1] = __builtin_bit_cast(float4, r.a[1]);
  union { float4 q[6]; float f[24]; } v1u;
#pragma unroll
  for (int i = 0; i < 6; ++i) v1u.q[i] = __builtin_bit_cast(float4, r.a[2 + i]);

  // ---- T1: sg(=kt) 0..2 x comp k 0..2 ; row = 3*zl + k (0..47)
#pragma unroll
  for (int sg = 0; sg < 3; ++sg) {
#pragma unroll
    for (int k = 0; k < 3; ++k) {
      int row = 3 * zl + k;
      int fl  = (((rr << 4) | (row & 15)) ^ sg) ^ rr;
      int slot = (row >> 4) * 192 + sg * 64 + fl;
      float t[8];
      if (sg == 0) {                     // s1 * v2[k]      (-> W2)
#pragma unroll
        for (int e = 0; e < 8; ++e) t[e] = s1u.f[e] * v2[k];
      } else if (sg == 1) {              // v1[.,k] * s2    (-> W3)
#pragma unroll
        for (int e = 0; e < 8; ++e) t[e] = v1u.f[3 * e + k] * s2;
      } else {                           // (v1 x v2)[k]    (-> W5)
        int k1 = k + 1; if (k1 > 2) k1 -= 3;
        int k2 = k + 2; if (k2 > 2) k2 -= 3;
#pragma unroll
        for (int e = 0; e < 8; ++e)
          t[e] = v1u.f[3 * e + k1] * v2[k2] - v1u.f[3 * e + k2] * v2[k1];
      }
      int4 pk;
      pk.x = cvtpk(t[0], t[1]); pk.y = cvtpk(t[2], t[3]);
      pk.z = cvtpk(t[4], t[5]); pk.w = cvtpk(t[6], t[7]);
      wbuf[slot] = pk;
    }
  }
  // ---- T0: sg(=kt) 0..1 ; row = zl
#pragma unroll
  for (int sg = 0; sg < 2; ++sg) {
    int fl = (((rr << 4) | zl) ^ sg) ^ rr;
    int slot = T0BASE + sg * 64 + fl;
    float t[8];
    if (sg == 0) {                       // s1 * s2         (-> W1)
#pragma unroll
      for (int e = 0; e < 8; ++e) t[e] = s1u.f[e] * s2;
    } else {                             // v1 . v2         (-> W4)
#pragma unroll
      for (int e = 0; e < 8; ++e) {
        const float* p = v1u.f + 3 * e;
        t[e] = p[0] * v2[0] + p[1] * v2[1] + p[2] * v2[2];
      }
    }
    int4 pk;
    pk.x = cvtpk(t[0], t[1]); pk.y = cvtpk(t[2], t[3]);
    pk.z = cvtpk(t[4], t[5]); pk.w = cvtpk(t[6], t[7]);
    wbuf[slot] = pk;
  }
}

// Burst-load this wave's per-chunk B slice (asm, stays in regs): 10 int4.
// vb[kt*2+j] = out1 (kt 0..2, j 0..1); vb[6+kt*2+j] = out0 (kt 0..1).
static __device__ __forceinline__ void burstB(
    ni4 (&vb)[10], const int4* __restrict__ B1v,
    const int4* __restrict__ B0v, int c, int ct0, int lane)
{
#pragma unroll
  for (int kt = 0; kt < 3; ++kt)
#pragma unroll
    for (int j = 0; j < 2; ++j)
      gload4(vb[kt * 2 + j],
             B1v + ((size_t)((c * 3 + kt) * 16 + ct0 + j)) * 64 + lane);
#pragma unroll
  for (int kt = 0; kt < 2; ++kt)
#pragma unroll
    for (int j = 0; j < 2; ++j)
      gload4(vb[6 + kt * 2 + j],
             B0v + ((size_t)((c * 2 + kt) * 16 + ct0 + j)) * 64 + lane);
}

// Pure LDS+MFMA gemm for one u-chunk: 22 MFMA. No barriers, no global loads.
static __device__ __forceinline__ void gemm_steps(
    const int4* __restrict__ wbuf, const ni4 (&vb)[10], int lane,
    f32x4 acc1[3][2], f32x4 acc0[2])
{
  __builtin_amdgcn_s_setprio(1);
#pragma unroll
  for (int kt = 0; kt < 3; ++kt) {
    int fl = (lane ^ kt) ^ (lane >> 4);
    int4 a[3];
#pragma unroll
    for (int rt = 0; rt < 3; ++rt) a[rt] = wbuf[rt * 192 + kt * 64 + fl];
#pragma unroll
    for (int rt = 0; rt < 3; ++rt) {
      bf16x8 av = asbf(a[rt]);
#pragma unroll
      for (int j = 0; j < 2; ++j)
        acc1[rt][j] = __builtin_amdgcn_mfma_f32_16x16x32_bf16(
            av, asbfn(vb[kt * 2 + j]), acc1[rt][j], 0, 0, 0);
    }
  }
#pragma unroll
  for (int kt = 0; kt < 2; ++kt) {
    int fl = (lane ^ kt) ^ (lane >> 4);
    int4 a0 = wbuf[T0BASE + kt * 64 + fl];
    bf16x8 av = asbf(a0);
#pragma unroll
    for (int j = 0; j < 2; ++j)
      acc0[j] = __builtin_amdgcn_mfma_f32_16x16x32_bf16(
          av, asbfn(vb[6 + kt * 2 + j]), acc0[j], 0, 0, 0);
  }
  __builtin_amdgcn_s_setprio(0);
}

// ---------------------------------------------------------------------------
// Main: ONE wave per block (64 thr). Wave = 16 z-rows x 32 cols.
// bid = zt*8 + colq. 8 u-chunks of 32; LDS 11.25 KB; zero barriers.
// ---------------------------------------------------------------------------
__global__ __launch_bounds__(64, 3) void tp_main(
    const float* __restrict__ x1, const float* __restrict__ x2,
    const int4* __restrict__ B1v, const int4* __restrict__ B0v,
    float* __restrict__ out)
{
  __shared__ int4 wbuf[704];            // 11264 bytes, wave-private
  const int lane = threadIdx.x & 63;
  const int colq = blockIdx.x & 7;
  const int ct0  = colq * 2;            // two 16-col tiles
  const int z0   = (blockIdx.x >> 3) * 16;
  const int zl   = lane >> 2;           // T-build row (0..15)
  const int rr   = lane & 3;            // T-build u-run (0..3)

  f32x4 acc1[3][2];
  f32x4 acc0[2];
#pragma unroll
  for (int i = 0; i < 3; ++i)
#pragma unroll
    for (int j = 0; j < 2; ++j) acc1[i][j] = (f32x4){0.f, 0.f, 0.f, 0.f};
#pragma unroll
  for (int j = 0; j < 2; ++j) acc0[j] = (f32x4){0.f, 0.f, 0.f, 0.f};

  // x2 (16B per z-row) via asm + drain BEFORE the pipeline starts.
  ni4 x2raw;
  gload4(x2raw, x2 + (size_t)(z0 + zl) * 4);
  WAITV(0);
  float4 x2v = __builtin_bit_cast(float4, x2raw);
  const float s2 = x2v.x;
  float v2[3] = {x2v.y, x2v.z, x2v.w};

  X1Raw rX;
  ni4 vb[10];

  load_x1_asm(rX, x1, z0 + zl, 0, rr);   // x1(0): 8 outstanding

#pragma unroll 1
  for (int c = 0; c < 7; ++c) {
    burstB(vb, B1v, B0v, c, ct0, lane);  // +10 -> 18
    WAITV(10);                           // x1(c) done; B(c) in flight
    build_frags(rX, zl, rr, s2, v2, wbuf);
    load_x1_asm(rX, x1, z0 + zl, (c + 1) * 32, rr);  // +8 -> 18
    WAITV(8);                            // B(c) done; x1(c+1) in flight
    gemm_steps(wbuf, vb, lane, acc1, acc0);
  }
  // ---- tail chunk 7
  burstB(vb, B1v, B0v, 7, ct0, lane);
  WAITV(10);                             // x1(7) done
  build_frags(rX, zl, rr, s2, v2, wbuf);
  WAITV(0);                              // B(7) done
  gemm_steps(wbuf, vb, lane, acc1, acc0);

  // ---- epilogue: accumulators are the final outputs
  const int col = lane & 15;
  const int rb  = (lane >> 4) * 4;       // C/D: col=lane&15, row=(lane>>4)*4+reg
#pragma unroll
  for (int j = 0; j < 2; ++j) {
    int w = (ct0 + j) * 16 + col;
#pragma unroll
    for (int rg = 0; rg < 4; ++rg) {
      int row = rb + rg;                 // zl 0..15
      out[(size_t)(z0 + row) * 1024 + w] = acc0[j][rg];
    }
  }
#pragma unroll
  for (int rt = 0; rt < 3; ++rt) {
#pragma unroll
    for (int j = 0; j < 2; ++j) {
      int w = (ct0 + j) * 16 + col;
#pragma unroll
      for (int rg = 0; rg < 4; ++rg) {
        int row = rt * 16 + rb + rg;     // 0..47 ; row = 3*zl + k
        int zz = row / 3;
        int k  = row - zz * 3;
        out[(size_t)(z0 + zz) * 1024 + 256 + w * 3 + k] = acc1[rt][j][rg];
      }
    }
  }
}

// ---------------------------------------------------------------------------
extern "C" void kernel_launch(void* const* d_in, const int* in_sizes, int n_in,
                              void* d_out, int out_size, void* d_ws, size_t ws_size,
                              hipStream_t stream) {
  const float* x1  = (const float*)d_in[0];   // (n, 1024) f32
  const float* x2  = (const float*)d_in[1];   // (n, 4)    f32
  const float* wgt = (const float*)d_in[2];   // (327680,) f32
  float* out = (float*)d_out;                 // (n, 1024) f32

  // ws: B1 fragments [0, 393216) + B0 fragments [393216, 655360)  (bf16)
  unsigned short* Bw = (unsigned short*)d_ws;
  const int4* B1v = (const int4*)Bw;
  const int4* B0v = B1v + 24576;

  int n = in_sizes[0] / 1024;                 // 20000 (divisible by 16)

  prep_weights<<<160, 256, 0, stream>>>(wgt, Bw);
  tp_main<<<(n / 16) * 8, 64, 0, stream>>>(x1, x2, B1v, B0v, out);
}

// Round 14
// 71.237 us; speedup vs baseline: 1.6531x; 1.6531x over previous
//
#include <hip/hip_runtime.h>

// Simple_TensorProduct (e3nn uvw TP, MUL=256, l<=1, v=1) as two fused bf16 GEMMs.
//   out0[z,w]      = sum_k T0[z,k]    * B0[k,w]   (K=512)
//   out1[(z,c),w]  = sum_k T1[(z,c),k]* B1[k,w]   (K=768, M=3N)
//
// R14 = R10 (best, 73.8us) + LDS-staged COALESCED epilogue.
// Theory: the scattered out1 store (stride-12B per lane, ~13 partial 64B
// lines per wave-store) creates ~3M L2 read-modify-write transactions that
// queue against B-loads. Stage out in LDS after the last gemm (24+8 KB, the
// T buffers are dead by then), read back linearly, store float4-coalesced.
// Everything before the epilogue is byte-identical to R10.

typedef short bf16x8 __attribute__((ext_vector_type(8)));
typedef float f32x4 __attribute__((ext_vector_type(4)));
typedef int   ni4   __attribute__((ext_vector_type(4)));

static __device__ __forceinline__ unsigned short f2bf(float f) {
  unsigned int u = __builtin_bit_cast(unsigned int, f);
  u += 0x7FFFu + ((u >> 16) & 1u);   // RNE
  return (unsigned short)(u >> 16);
}

static __device__ __forceinline__ bf16x8 asbf(int4 v) {
  return __builtin_bit_cast(bf16x8, v);
}
static __device__ __forceinline__ bf16x8 asbfn(ni4 v) {
  return __builtin_bit_cast(bf16x8, v);
}

static __device__ __forceinline__ void gload4(ni4& dst, const void* p) {
  asm volatile("global_load_dwordx4 %0, %1, off" : "=v"(dst) : "v"(p));
}

#define WAITV(n) do { \
    asm volatile("s_waitcnt vmcnt(" #n ")"); \
    __builtin_amdgcn_sched_barrier(0); \
  } while (0)

static __device__ __forceinline__ void phase_barrier() {
  __builtin_amdgcn_sched_barrier(0);
  asm volatile("s_waitcnt lgkmcnt(0)");
  __builtin_amdgcn_sched_barrier(0);
  __builtin_amdgcn_s_barrier();
  __builtin_amdgcn_sched_barrier(0);
}

// ---------------------------------------------------------------------------
// Weight prep (u-chunk = 64, c in 0..3; verbatim R10, passed):
// B1: fid = ((c*6+kt)*16+ct)*64+lane; elem e: kc=kt*32+(lane>>4)*8+e (0..191),
//     seg=kc>>6, u=c*64+(kc&63), w=ct*16+(lane&15)
// B0: fid = 24576 + ((c*4+kt)*16+ct)*64+lane; kc 0..127, seg=kc>>6
// ---------------------------------------------------------------------------
__global__ __launch_bounds__(256) void prep_weights(
    const float* __restrict__ wgt, unsigned short* __restrict__ Bw)
{
  int fid = blockIdx.x * 256 + threadIdx.x;
  union { unsigned short h[8]; int4 v; } pk;
  if (fid < 24576) {
    int lane = fid & 63;
    int ct = (fid >> 6) & 15;
    int q = fid >> 10;            // 0..23 = c*6 + kt
    int kt = q % 6, c = q / 6;
    int w = ct * 16 + (lane & 15);
    int kh = (lane >> 4) * 8;
#pragma unroll
    for (int e = 0; e < 8; ++e) {
      int kc = kt * 32 + kh + e;       // 0..191
      int seg = kc >> 6;
      int u = c * 64 + (kc & 63);
      float s  = (seg == 2) ? 0.025515518153991442f : 0.03608439182435161f;
      int off  = (seg == 0) ? 65536 : (seg == 1 ? 131072 : 262144);
      pk.h[e] = f2bf(wgt[off + u * 256 + w] * s);
    }
    ((int4*)Bw)[fid] = pk.v;
  } else if (fid < 40960) {
    int f2 = fid - 24576;
    int lane = f2 & 63;
    int ct = (f2 >> 6) & 15;
    int q = f2 >> 10;             // 0..15 = c*4 + kt
    int kt = q & 3, c = q >> 2;
    int w = ct * 16 + (lane & 15);
    int kh = (lane >> 4) * 8;
#pragma unroll
    for (int e = 0; e < 8; ++e) {
      int kc = kt * 32 + kh + e;       // 0..127
      int seg = kc >> 6;
      int u = c * 64 + (kc & 63);
      float s  = (seg == 0) ? 0.04419417382415922f : 0.025515518153991442f;
      int off  = (seg == 0) ? 0 : 196608;
      pk.h[e] = f2bf(wgt[off + u * 256 + w] * s);
    }
    ((int4*)Bw)[fid] = pk.v;
  }
}

#define BUFSLOTS 1408
#define T0BASE 1152

struct X1Raw { ni4 a0, a1, a2, a3; };   // s1[4] + v1[4u x 3k] raw bits

static __device__ __forceinline__ void load_x1_asm(
    X1Raw& r, const float* __restrict__ x1, int zrow, int ub, int rr)
{
  const float* base = x1 + (size_t)zrow * 1024;
  gload4(r.a0, base + ub + rr * 4);
  const float* pv = base + 256 + 3 * ub + rr * 12;
  gload4(r.a1, pv);
  gload4(r.a2, pv + 4);
  gload4(r.a3, pv + 8);
}

// thread (zl 0..15, rr 0..15) owns u-run [rr*4, rr*4+4) of the 64-u chunk.
// kc = sg*64 + rr*4 + e -> kt = sg*2 + (rr>>3), lh = (rr>>1)&3, half = rr&1.
static __device__ __forceinline__ void build_frags(
    const X1Raw& r, int zl, int rr, float s2, const float* v2, int4* ldsT)
{
  union { float4 q; float f[4]; } s1u;
  s1u.q = __builtin_bit_cast(float4, r.a0);
  union { float4 q[3]; float f[12]; } v1u;
  v1u.q[0] = __builtin_bit_cast(float4, r.a1);
  v1u.q[1] = __builtin_bit_cast(float4, r.a2);
  v1u.q[2] = __builtin_bit_cast(float4, r.a3);
  const int lh   = (rr >> 1) & 3;
  const int kq   = rr >> 3;
  const int half = rr & 1;
  int2* lds2 = (int2*)ldsT;

  // ---- T1: seg 0..2 x comp k 0..2 ; row = 3*zl + k (0..47)
#pragma unroll
  for (int sg = 0; sg < 3; ++sg) {
#pragma unroll
    for (int k = 0; k < 3; ++k) {
      int row = 3 * zl + k;
      int kt  = sg * 2 + kq;
      int fl  = (((lh << 4) | (row & 15)) ^ (kt & 7)) ^ lh;
      int slot = (row >> 4) * 384 + kt * 64 + fl;
      float t[4];
      if (sg == 0) {                     // s1 * v2[k]      (-> W2)
#pragma unroll
        for (int e = 0; e < 4; ++e) t[e] = s1u.f[e] * v2[k];
      } else if (sg == 1) {              // v1[.,k] * s2    (-> W3)
#pragma unroll
        for (int e = 0; e < 4; ++e) t[e] = v1u.f[3 * e + k] * s2;
      } else {                           // (v1 x v2)[k]    (-> W5)
        int k1 = k + 1; if (k1 > 2) k1 -= 3;
        int k2 = k + 2; if (k2 > 2) k2 -= 3;
#pragma unroll
        for (int e = 0; e < 4; ++e)
          t[e] = v1u.f[3 * e + k1] * v2[k2] - v1u.f[3 * e + k2] * v2[k1];
      }
      union { unsigned short h[4]; int2 v; } pk;
#pragma unroll
      for (int e = 0; e < 4; ++e) pk.h[e] = f2bf(t[e]);
      lds2[slot * 2 + half] = pk.v;
    }
  }
  // ---- T0: seg 0..1 ; row = zl (0..15)
#pragma unroll
  for (int sg = 0; sg < 2; ++sg) {
    int kt = sg * 2 + kq;
    int fl = (((lh << 4) | zl) ^ (kt & 7)) ^ lh;
    int slot = T0BASE + kt * 64 + fl;
    float t[4];
    if (sg == 0) {                       // s1 * s2         (-> W1)
#pragma unroll
      for (int e = 0; e < 4; ++e) t[e] = s1u.f[e] * s2;
    } else {                             // v1 . v2         (-> W4)
#pragma unroll
      for (int e = 0; e < 4; ++e)
        t[e] = v1u.f[3 * e] * v2[0] + v1u.f[3 * e + 1] * v2[1]
             + v1u.f[3 * e + 2] * v2[2];
    }
    union { unsigned short h[4]; int2 v; } pk;
#pragma unroll
    for (int e = 0; e < 4; ++e) pk.h[e] = f2bf(t[e]);
    lds2[slot * 2 + half] = pk.v;
  }
}

// Burst-load this wave's ENTIRE per-chunk B slice as asm: 20 int4 (80 VGPR).
static __device__ __forceinline__ void burstB(
    ni4 (&vb)[20], const int4* __restrict__ B1v,
    const int4* __restrict__ B0v, int c, int ct0, int lane)
{
#pragma unroll
  for (int s = 0; s < 6; ++s) {
    const int4* p = B1v + ((size_t)((c * 6 + s) * 16 + ct0)) * 64 + lane;
    gload4(vb[s * 2],     p);
    gload4(vb[s * 2 + 1], p + 64);
  }
#pragma unroll
  for (int s = 0; s < 4; ++s) {
    const int4* p = B0v + ((size_t)((c * 4 + s) * 16 + ct0)) * 64 + lane;
    gload4(vb[12 + s * 2],     p);
    gload4(vb[12 + s * 2 + 1], p + 64);
  }
}

// Pure LDS+MFMA gemm for one u-chunk (no global loads). Identical to R10.
static __device__ __forceinline__ void gemm_steps(
    const int4* __restrict__ buf, const ni4 (&vb)[20], int lane,
    f32x4 acc1[3][2], f32x4 acc0[2])
{
#pragma unroll
  for (int kt = 0; kt < 6; ++kt) {
    int fl = (lane ^ (kt & 7)) ^ (lane >> 4);
    int4 a0 = buf[kt * 64 + fl];
    int4 a1 = buf[384 + kt * 64 + fl];
    int4 a2 = buf[768 + kt * 64 + fl];
    int4 a[3] = {a0, a1, a2};
#pragma unroll
    for (int rt = 0; rt < 3; ++rt) {
      bf16x8 av = asbf(a[rt]);
#pragma unroll
      for (int j = 0; j < 2; ++j)
        acc1[rt][j] = __builtin_amdgcn_mfma_f32_16x16x32_bf16(
            av, asbfn(vb[kt * 2 + j]), acc1[rt][j], 0, 0, 0);
    }
  }
#pragma unroll
  for (int kt = 0; kt < 4; ++kt) {
    int fl = (lane ^ (kt & 7)) ^ (lane >> 4);
    int4 a0 = buf[T0BASE + kt * 64 + fl];
    bf16x8 av = asbf(a0);
#pragma unroll
    for (int j = 0; j < 2; ++j)
      acc0[j] = __builtin_amdgcn_mfma_f32_16x16x32_bf16(
          av, asbfn(vb[12 + kt * 2 + j]), acc0[j], 0, 0, 0);
  }
}

// ---------------------------------------------------------------------------
// Main: 256 threads (4 waves, ct=2 each -> 128 cols), w-split across 2 blocks
// per z-tile (grid 2500). 16 z-rows, 4 u-chunks of 64, double-buffered LDS.
// ---------------------------------------------------------------------------
__global__ __launch_bounds__(256, 2) void tp_main(
    const float* __restrict__ x1, const float* __restrict__ x2,
    const int4* __restrict__ B1v, const int4* __restrict__ B0v,
    float* __restrict__ out)
{
  __shared__ int4 ldsT[2 * BUFSLOTS];   // 45056 bytes
  const int tid  = threadIdx.x;
  const int lane = tid & 63;
  const int wid  = tid >> 6;            // wave 0..3
  const int wh   = blockIdx.x & 1;      // w-half
  const int ct0  = wh * 8 + wid * 2;    // this wave's two 16-col tiles (global)
  const int z0   = (blockIdx.x >> 1) * 16;
  const int zl   = tid >> 4;            // T-build row (0..15)
  const int rr   = tid & 15;            // T-build u-run (0..15)

  f32x4 acc1[3][2];
  f32x4 acc0[2];
#pragma unroll
  for (int i = 0; i < 3; ++i)
#pragma unroll
    for (int j = 0; j < 2; ++j) acc1[i][j] = (f32x4){0.f, 0.f, 0.f, 0.f};
#pragma unroll
  for (int j = 0; j < 2; ++j) acc0[j] = (f32x4){0.f, 0.f, 0.f, 0.f};

  float4 x2v = ((const float4*)x2)[z0 + zl];   // normal load (compiler-waited)
  const float s2 = x2v.x;
  float v2[3] = {x2v.y, x2v.z, x2v.w};

  X1Raw rA, rB;
  ni4 vb[20];

  // prologue: x1(0)->rA, x1(1)->rB in flight (8 outstanding)
  load_x1_asm(rA, x1, z0 + zl, 0, rr);
  load_x1_asm(rB, x1, z0 + zl, 64, rr);
  WAITV(4);                              // x1(0) done, x1(1) in flight
  build_frags(rA, zl, rr, s2, v2, ldsT);
  phase_barrier();

  // ---- phase 0: gemm(0,buf0) ; build(1)->buf1 ; x1(2)->rA
  burstB(vb, B1v, B0v, 0, ct0, lane);    // out: 4 + 10 = 14
  load_x1_asm(rA, x1, z0 + zl, 128, rr); // out: 18
  WAITV(14);                             // x1(1) done
  build_frags(rB, zl, rr, s2, v2, ldsT + BUFSLOTS);
  WAITV(4);                              // B(0) done, x1(2) in flight
  gemm_steps(ldsT, vb, lane, acc1, acc0);
  phase_barrier();

  // ---- phase 1: gemm(1,buf1) ; build(2)->buf0 ; x1(3)->rB
  burstB(vb, B1v, B0v, 1, ct0, lane);    // out: 4 + 10 = 14
  load_x1_asm(rB, x1, z0 + zl, 192, rr); // out: 18
  WAITV(14);                             // x1(2) done
  build_frags(rA, zl, rr, s2, v2, ldsT);
  WAITV(4);                              // B(1) done, x1(3) in flight
  gemm_steps(ldsT + BUFSLOTS, vb, lane, acc1, acc0);
  phase_barrier();

  // ---- phase 2: gemm(2,buf0) ; build(3)->buf1
  burstB(vb, B1v, B0v, 2, ct0, lane);    // out: 4 + 10 = 14
  WAITV(10);                             // x1(3) done
  build_frags(rB, zl, rr, s2, v2, ldsT + BUFSLOTS);
  WAITV(0);                              // B(2) done
  gemm_steps(ldsT, vb, lane, acc1, acc0);
  phase_barrier();

  // ---- phase 3: gemm(3,buf1)
  burstB(vb, B1v, B0v, 3, ct0, lane);    // out: 10
  WAITV(0);                              // B(3) done
  gemm_steps(ldsT + BUFSLOTS, vb, lane, acc1, acc0);

  // ==== NEW EPILOGUE: stage in LDS, store coalesced ====
  phase_barrier();                       // all waves done reading T buffers
  float* ldsF = (float*)ldsT;            // lds1: [0,6144) = 16 x 384 (out1)
                                         // lds0: [6144,8192) = 16 x 128 (out0)
  const int col = lane & 15;
  const int rb  = (lane >> 4) * 4;       // C/D: col=lane&15, row=(lane>>4)*4+reg
#pragma unroll
  for (int j = 0; j < 2; ++j) {
    int wl = wid * 32 + j * 16 + col;    // block-local w (0..127)
#pragma unroll
    for (int rg = 0; rg < 4; ++rg) {
      int row = rb + rg;                 // zl 0..15
      ldsF[6144 + row * 128 + wl] = acc0[j][rg];
    }
  }
#pragma unroll
  for (int rt = 0; rt < 3; ++rt) {
#pragma unroll
    for (int j = 0; j < 2; ++j) {
      int wl = wid * 32 + j * 16 + col;
#pragma unroll
      for (int rg = 0; rg < 4; ++rg) {
        int row = rt * 16 + rb + rg;     // 0..47 ; row = 3*zl + k
        int zz = row / 3;
        int k  = row - zz * 3;
        ldsF[zz * 384 + wl * 3 + k] = acc1[rt][j][rg];
      }
    }
  }
  phase_barrier();                       // stage complete

  // out1: 16 rows x 384 floats contiguous at out[(z)*1024 + 256 + wh*384]
  const float4* lds4 = (const float4*)ldsF;
#pragma unroll
  for (int i = 0; i < 6; ++i) {
    int idx = i * 256 + tid;             // 0..1535
    int row = idx / 96;
    int c4  = idx - row * 96;
    float4 v = lds4[row * 96 + c4];
    *(float4*)(out + (size_t)(z0 + row) * 1024 + 256 + wh * 384 + c4 * 4) = v;
  }
  // out0: 16 rows x 128 floats contiguous at out[(z)*1024 + wh*128]
#pragma unroll
  for (int i = 0; i < 2; ++i) {
    int idx = i * 256 + tid;             // 0..511
    int row = idx >> 5;
    int c4  = idx & 31;
    float4 v = lds4[1536 + row * 32 + c4];
    *(float4*)(out + (size_t)(z0 + row) * 1024 + wh * 128 + c4 * 4) = v;
  }
}

// ---------------------------------------------------------------------------
extern "C" void kernel_launch(void* const* d_in, const int* in_sizes, int n_in,
                              void* d_out, int out_size, void* d_ws, size_t ws_size,
                              hipStream_t stream) {
  const float* x1  = (const float*)d_in[0];   // (n, 1024) f32
  const float* x2  = (const float*)d_in[1];   // (n, 4)    f32
  const float* wgt = (const float*)d_in[2];   // (327680,) f32
  float* out = (float*)d_out;                 // (n, 1024) f32

  // ws: B1 fragments [0, 393216) + B0 fragments [393216, 655360)  (bf16)
  unsigned short* Bw = (unsigned short*)d_ws;
  const int4* B1v = (const int4*)Bw;
  const int4* B0v = B1v + 24576;

  int n = in_sizes[0] / 1024;                 // 20000 (divisible by 16)

  prep_weights<<<160, 256, 0, stream>>>(wgt, Bw);
  tp_main<<<(n / 16) * 2, 256, 0, stream>>>(x1, x2, B1v, B0v, out);
}

// Round 16
// 62.914 us; speedup vs baseline: 1.8717x; 1.1323x over previous
//
#include <hip/hip_runtime.h>

// Simple_TensorProduct (e3nn uvw TP, MUL=256, l<=1, v=1) as two fused bf16 GEMMs.
//   out0[z,w]      = sum_k T0[z,k]    * B0[k,w]   (K=512)
//   out1[(z,c),w]  = sum_k T1[(z,c),k]* B1[k,w]   (K=768, M=3N)
//
// R16 = R15 fixed. Crash cause: runtime-selected asm-load destinations
// ((c&1)? rA : rB) in a rolled loop -> compiler register copies/reuse while
// loads in flight -> clobber -> GPU fault. Now six EXPLICIT phases with
// static rA/rB parity. Also fixed: phase 6 builds chunk 7 from rB (was rA).
// Design: phase-staggered blocks (cs = 0 or 4 by block pair), u-chunk 32,
// LDS 32 KB, launch_bounds(256,4) -> 4 resident blocks/CU; R14 epilogue.

typedef short bf16x8 __attribute__((ext_vector_type(8)));
typedef float f32x4 __attribute__((ext_vector_type(4)));
typedef int   ni4   __attribute__((ext_vector_type(4)));
typedef int   ni2   __attribute__((ext_vector_type(2)));

static __device__ __forceinline__ unsigned short f2bf(float f) {
  unsigned int u = __builtin_bit_cast(unsigned int, f);
  u += 0x7FFFu + ((u >> 16) & 1u);   // RNE (prep kernel only)
  return (unsigned short)(u >> 16);
}

// 2x f32 -> packed bf16x2, RNE, single instruction. lo -> D[15:0].
static __device__ __forceinline__ int cvtpk(float lo, float hi) {
  int r;
  asm("v_cvt_pk_bf16_f32 %0, %1, %2" : "=v"(r) : "v"(lo), "v"(hi));
  return r;
}

static __device__ __forceinline__ bf16x8 asbf(int4 v) {
  return __builtin_bit_cast(bf16x8, v);
}
static __device__ __forceinline__ bf16x8 asbfn(ni4 v) {
  return __builtin_bit_cast(bf16x8, v);
}

static __device__ __forceinline__ void gload4(ni4& dst, const void* p) {
  asm volatile("global_load_dwordx4 %0, %1, off" : "=v"(dst) : "v"(p));
}
static __device__ __forceinline__ void gload2(ni2& dst, const void* p) {
  asm volatile("global_load_dwordx2 %0, %1, off" : "=v"(dst) : "v"(p));
}

#define WAITV(n) do { \
    asm volatile("s_waitcnt vmcnt(" #n ")"); \
    __builtin_amdgcn_sched_barrier(0); \
  } while (0)

static __device__ __forceinline__ void phase_barrier() {
  __builtin_amdgcn_sched_barrier(0);
  asm volatile("s_waitcnt lgkmcnt(0)");
  __builtin_amdgcn_sched_barrier(0);
  __builtin_amdgcn_s_barrier();
  __builtin_amdgcn_sched_barrier(0);
}

// ---------------------------------------------------------------------------
// Weight prep (verbatim R12/R13, passed): u-chunk = 32, c in 0..7, kt==seg.
// B1: fid = ((c*3+kt)*16+ct)*64+lane; elem e: kc=kt*32+(lane>>4)*8+e (0..95),
//     seg=kc>>5, u=c*32+(kc&31), w=ct*16+(lane&15)
// B0: fid = 24576 + ((c*2+kt)*16+ct)*64+lane; kc 0..63, seg=kc>>5
// ---------------------------------------------------------------------------
__global__ __launch_bounds__(256) void prep_weights(
    const float* __restrict__ wgt, unsigned short* __restrict__ Bw)
{
  int fid = blockIdx.x * 256 + threadIdx.x;
  union { unsigned short h[8]; int4 v; } pk;
  if (fid < 24576) {
    int lane = fid & 63;
    int ct = (fid >> 6) & 15;
    int q = fid >> 10;            // 0..23 = c*3 + kt
    int kt = q % 3, c = q / 3;
    int w = ct * 16 + (lane & 15);
    int kh = (lane >> 4) * 8;
#pragma unroll
    for (int e = 0; e < 8; ++e) {
      int kc = kt * 32 + kh + e;       // 0..95
      int seg = kc >> 5;
      int u = c * 32 + (kc & 31);
      float s  = (seg == 2) ? 0.025515518153991442f : 0.03608439182435161f;
      int off  = (seg == 0) ? 65536 : (seg == 1 ? 131072 : 262144);
      pk.h[e] = f2bf(wgt[off + u * 256 + w] * s);
    }
    ((int4*)Bw)[fid] = pk.v;
  } else if (fid < 40960) {
    int f2 = fid - 24576;
    int lane = f2 & 63;
    int ct = (f2 >> 6) & 15;
    int q = f2 >> 10;             // 0..15 = c*2 + kt
    int kt = q & 1, c = q >> 1;
    int w = ct * 16 + (lane & 15);
    int kh = (lane >> 4) * 8;
#pragma unroll
    for (int e = 0; e < 8; ++e) {
      int kc = kt * 32 + kh + e;       // 0..63
      int seg = kc >> 5;
      int u = c * 32 + (kc & 31);
      float s  = (seg == 0) ? 0.04419417382415922f : 0.025515518153991442f;
      int off  = (seg == 0) ? 0 : 196608;
      pk.h[e] = f2bf(wgt[off + u * 256 + w] * s);
    }
    ((int4*)Bw)[fid] = pk.v;
  }
}

// Per-buffer LDS map (int4 slots, 704 = 11.25 KB), R12's map (passed):
//   T1: rt*192 + sg*64 + fl   (rt 0..2, sg 0..2)
//   T0: 576 + sg*64 + fl      (sg 0..1)
#define BUFSLOTS 704
#define T0BASE 576

struct X1R2 { ni2 s, v0, v1, v2; };   // s1[2] + v1[2u x 3k] raw bits (4 loads)

static __device__ __forceinline__ void load_x1_2(
    X1R2& r, const float* __restrict__ x1, int zrow, int ub, int rr)
{
  const float* base = x1 + (size_t)zrow * 1024;
  gload2(r.s,  base + ub + rr * 2);
  const float* pv = base + 256 + 3 * ub + rr * 6;
  gload2(r.v0, pv);
  gload2(r.v1, pv + 2);
  gload2(r.v2, pv + 4);
}

// thread (zl = tid>>4 0..15, rr = tid&15) owns u-pair [rr*2, rr*2+2) of the
// 32-u chunk. kt==sg; lane-half lh = rr>>2; dword q = rr&3.
static __device__ __forceinline__ void build_frags(
    const X1R2& r, int zl, int rr, float s2, const float* v2,
    unsigned int* __restrict__ lds32)
{
  float2 sf = __builtin_bit_cast(float2, r.s);
  float2 va = __builtin_bit_cast(float2, r.v0);
  float2 vb = __builtin_bit_cast(float2, r.v1);
  float2 vc = __builtin_bit_cast(float2, r.v2);
  float s1f[2] = {sf.x, sf.y};
  float vf[6] = {va.x, va.y, vb.x, vb.y, vc.x, vc.y};  // vf[3e+k]
  const int lh = rr >> 2;
  const int q  = rr & 3;

  // ---- T1: sg(=kt) 0..2 x comp k 0..2 ; row = 3*zl + k (0..47)
#pragma unroll
  for (int sg = 0; sg < 3; ++sg) {
#pragma unroll
    for (int k = 0; k < 3; ++k) {
      int row = 3 * zl + k;
      int fl  = (((lh << 4) | (row & 15)) ^ sg) ^ lh;
      int slot = (row >> 4) * 192 + sg * 64 + fl;
      float t0, t1;
      if (sg == 0) {                     // s1 * v2[k]      (-> W2)
        t0 = s1f[0] * v2[k]; t1 = s1f[1] * v2[k];
      } else if (sg == 1) {              // v1[.,k] * s2    (-> W3)
        t0 = vf[k] * s2; t1 = vf[3 + k] * s2;
      } else {                           // (v1 x v2)[k]    (-> W5)
        int k1 = k + 1; if (k1 > 2) k1 -= 3;
        int k2 = k + 2; if (k2 > 2) k2 -= 3;
        t0 = vf[k1] * v2[k2] - vf[k2] * v2[k1];
        t1 = vf[3 + k1] * v2[k2] - vf[3 + k2] * v2[k1];
      }
      lds32[slot * 4 + q] = (unsigned int)cvtpk(t0, t1);
    }
  }
  // ---- T0: sg(=kt) 0..1 ; row = zl
#pragma unroll
  for (int sg = 0; sg < 2; ++sg) {
    int fl = (((lh << 4) | zl) ^ sg) ^ lh;
    int slot = T0BASE + sg * 64 + fl;
    float t0, t1;
    if (sg == 0) {                       // s1 * s2         (-> W1)
      t0 = s1f[0] * s2; t1 = s1f[1] * s2;
    } else {                             // v1 . v2         (-> W4)
      t0 = vf[0] * v2[0] + vf[1] * v2[1] + vf[2] * v2[2];
      t1 = vf[3] * v2[0] + vf[4] * v2[1] + vf[5] * v2[2];
    }
    lds32[slot * 4 + q] = (unsigned int)cvtpk(t0, t1);
  }
}

// Burst-load this wave's per-chunk B slice (asm, static dests): 10 int4.
static __device__ __forceinline__ void burstB(
    ni4 (&vb)[10], const int4* __restrict__ B1v,
    const int4* __restrict__ B0v, int c, int ct0, int lane)
{
#pragma unroll
  for (int kt = 0; kt < 3; ++kt)
#pragma unroll
    for (int j = 0; j < 2; ++j)
      gload4(vb[kt * 2 + j],
             B1v + ((size_t)((c * 3 + kt) * 16 + ct0 + j)) * 64 + lane);
#pragma unroll
  for (int kt = 0; kt < 2; ++kt)
#pragma unroll
    for (int j = 0; j < 2; ++j)
      gload4(vb[6 + kt * 2 + j],
             B0v + ((size_t)((c * 2 + kt) * 16 + ct0 + j)) * 64 + lane);
}

// Pure LDS+MFMA gemm for one u-chunk: 22 MFMA. (verbatim R13, passed)
static __device__ __forceinline__ void gemm_steps(
    const int4* __restrict__ buf, const ni4 (&vb)[10], int lane,
    f32x4 acc1[3][2], f32x4 acc0[2])
{
  __builtin_amdgcn_s_setprio(1);
#pragma unroll
  for (int kt = 0; kt < 3; ++kt) {
    int fl = (lane ^ kt) ^ (lane >> 4);
    int4 a[3];
#pragma unroll
    for (int rt = 0; rt < 3; ++rt) a[rt] = buf[rt * 192 + kt * 64 + fl];
#pragma unroll
    for (int rt = 0; rt < 3; ++rt) {
      bf16x8 av = asbf(a[rt]);
#pragma unroll
      for (int j = 0; j < 2; ++j)
        acc1[rt][j] = __builtin_amdgcn_mfma_f32_16x16x32_bf16(
            av, asbfn(vb[kt * 2 + j]), acc1[rt][j], 0, 0, 0);
    }
  }
#pragma unroll
  for (int kt = 0; kt < 2; ++kt) {
    int fl = (lane ^ kt) ^ (lane >> 4);
    int4 a0 = buf[T0BASE + kt * 64 + fl];
    bf16x8 av = asbf(a0);
#pragma unroll
    for (int j = 0; j < 2; ++j)
      acc0[j] = __builtin_amdgcn_mfma_f32_16x16x32_bf16(
          av, asbfn(vb[6 + kt * 2 + j]), acc0[j], 0, 0, 0);
  }
  __builtin_amdgcn_s_setprio(0);
}

// ---------------------------------------------------------------------------
// Main: 256 thr (4 waves, ct=2 -> 128 cols), w-split (grid 2500), z=16.
// 8 u-chunks of 32, dbuf LDS; chunk order staggered per block pair (^cs).
// Explicit phases; all asm-load destinations statically named.
// ---------------------------------------------------------------------------
__global__ __launch_bounds__(256, 4) void tp_main(
    const float* __restrict__ x1, const float* __restrict__ x2,
    const int4* __restrict__ B1v, const int4* __restrict__ B0v,
    float* __restrict__ out)
{
  __shared__ int4 ldsT[2048];           // 32768 bytes (T dbuf uses first 1408)
  const int tid  = threadIdx.x;
  const int lane = tid & 63;
  const int wid  = tid >> 6;            // wave 0..3
  const int wh   = blockIdx.x & 1;      // w-half
  const int ct0  = wh * 8 + wid * 2;    // this wave's two 16-col tiles (global)
  const int z0   = (blockIdx.x >> 1) * 16;
  const int zl   = tid >> 4;            // T-build row (0..15)
  const int rr   = tid & 15;            // T-build u-pair (0..15)
  const int cs   = (blockIdx.x & 2) << 1;  // 0 or 4: phase stagger

  f32x4 acc1[3][2];
  f32x4 acc0[2];
#pragma unroll
  for (int i = 0; i < 3; ++i)
#pragma unroll
    for (int j = 0; j < 2; ++j) acc1[i][j] = (f32x4){0.f, 0.f, 0.f, 0.f};
#pragma unroll
  for (int j = 0; j < 2; ++j) acc0[j] = (f32x4){0.f, 0.f, 0.f, 0.f};

  // x2 via asm + FULL drain before the pipeline: no compiler VMEM mid-pipe.
  ni4 x2raw;
  gload4(x2raw, x2 + (size_t)(z0 + zl) * 4);
  WAITV(0);
  float4 x2v = __builtin_bit_cast(float4, x2raw);
  const float s2 = x2v.x;
  float v2[3] = {x2v.y, x2v.z, x2v.w};

  unsigned int* lds32_0 = (unsigned int*)ldsT;
  unsigned int* lds32_1 = (unsigned int*)(ldsT + BUFSLOTS);

  X1R2 rA, rB;
  ni4 vb[10];

  // prologue: chunk c0 -> rA, c1 -> rB (8 outstanding); build c0 -> buf0
  load_x1_2(rA, x1, z0 + zl, (0 ^ cs) * 32, rr);
  load_x1_2(rB, x1, z0 + zl, (1 ^ cs) * 32, rr);
  WAITV(4);                              // rA ready
  build_frags(rA, zl, rr, s2, v2, lds32_0);
  phase_barrier();

  // Phase c (0..5): gemm chunk c from BUFG; build chunk c+1 (in RB_) -> BUFB;
  // issue x1 chunk c+2 -> RL_. All names static per phase.
#define PHASE(C, RL_, RB_, BUFB, BUFG) \
  burstB(vb, B1v, B0v, (C) ^ cs, ct0, lane);                    /* -> 14 */ \
  load_x1_2(RL_, x1, z0 + zl, (((C) + 2) ^ cs) * 32, rr);       /* -> 18 */ \
  WAITV(14);                             /* x1(c+1) ready */               \
  build_frags(RB_, zl, rr, s2, v2, BUFB);                                  \
  WAITV(4);                              /* B(c) ready */                  \
  gemm_steps(BUFG, vb, lane, acc1, acc0);                                  \
  phase_barrier();

  PHASE(0, rA, rB, lds32_1, ldsT)             // gemm c0; build c1; load c2
  PHASE(1, rB, rA, lds32_0, ldsT + BUFSLOTS)  // gemm c1; build c2; load c3
  PHASE(2, rA, rB, lds32_1, ldsT)             // gemm c2; build c3; load c4
  PHASE(3, rB, rA, lds32_0, ldsT + BUFSLOTS)  // gemm c3; build c4; load c5
  PHASE(4, rA, rB, lds32_1, ldsT)             // gemm c4; build c5; load c6
  PHASE(5, rB, rA, lds32_0, ldsT + BUFSLOTS)  // gemm c5; build c6; load c7
#undef PHASE

  // ---- phase 6: gemm c6 (buf0); build c7 (rB) -> buf1
  burstB(vb, B1v, B0v, 6 ^ cs, ct0, lane);    // 4 + 10 = 14
  WAITV(10);                             // x1(c7) ready (rB)
  build_frags(rB, zl, rr, s2, v2, lds32_1);
  WAITV(0);                              // B(c6) ready
  gemm_steps(ldsT, vb, lane, acc1, acc0);
  phase_barrier();
  // ---- phase 7: gemm c7 (buf1)
  burstB(vb, B1v, B0v, 7 ^ cs, ct0, lane);
  WAITV(0);
  gemm_steps(ldsT + BUFSLOTS, vb, lane, acc1, acc0);

  // ==== epilogue: stage in LDS, store coalesced (verbatim R14, passed) ====
  phase_barrier();                       // all waves done reading T buffers
  float* ldsF = (float*)ldsT;            // [0,6144) out1 16x384; [6144,8192) out0
  const int col = lane & 15;
  const int rb  = (lane >> 4) * 4;       // C/D: col=lane&15, row=(lane>>4)*4+reg
#pragma unroll
  for (int j = 0; j < 2; ++j) {
    int wl = wid * 32 + j * 16 + col;    // block-local w (0..127)
#pragma unroll
    for (int rg = 0; rg < 4; ++rg) {
      int row = rb + rg;                 // zl 0..15
      ldsF[6144 + row * 128 + wl] = acc0[j][rg];
    }
  }
#pragma unroll
  for (int rt = 0; rt < 3; ++rt) {
#pragma unroll
    for (int j = 0; j < 2; ++j) {
      int wl = wid * 32 + j * 16 + col;
#pragma unroll
      for (int rg = 0; rg < 4; ++rg) {
        int row = rt * 16 + rb + rg;     // 0..47 ; row = 3*zl + k
        int zz = row / 3;
        int k  = row - zz * 3;
        ldsF[zz * 384 + wl * 3 + k] = acc1[rt][j][rg];
      }
    }
  }
  phase_barrier();                       // stage complete

  const float4* lds4 = (const float4*)ldsF;
#pragma unroll
  for (int i = 0; i < 6; ++i) {
    int idx = i * 256 + tid;             // 0..1535
    int row = idx / 96;
    int c4  = idx - row * 96;
    float4 v = lds4[row * 96 + c4];
    *(float4*)(out + (size_t)(z0 + row) * 1024 + 256 + wh * 384 + c4 * 4) = v;
  }
#pragma unroll
  for (int i = 0; i < 2; ++i) {
    int idx = i * 256 + tid;             // 0..511
    int row = idx >> 5;
    int c4  = idx & 31;
    float4 v = lds4[1536 + row * 32 + c4];
    *(float4*)(out + (size_t)(z0 + row) * 1024 + wh * 128 + c4 * 4) = v;
  }
}

// ---------------------------------------------------------------------------
extern "C" void kernel_launch(void* const* d_in, const int* in_sizes, int n_in,
                              void* d_out, int out_size, void* d_ws, size_t ws_size,
                              hipStream_t stream) {
  const float* x1  = (const float*)d_in[0];   // (n, 1024) f32
  const float* x2  = (const float*)d_in[1];   // (n, 4)    f32
  const float* wgt = (const float*)d_in[2];   // (327680,) f32
  float* out = (float*)d_out;                 // (n, 1024) f32

  // ws: B1 fragments [0, 393216) + B0 fragments [393216, 655360)  (bf16)
  unsigned short* Bw = (unsigned short*)d_ws;
  const int4* B1v = (const int4*)Bw;
  const int4* B0v = B1v + 24576;

  int n = in_sizes[0] / 1024;                 // 20000 (divisible by 16)

  prep_weights<<<160, 256, 0, stream>>>(wgt, Bw);
  tp_main<<<(n / 16) * 2, 256, 0, stream>>>(x1, x2, B1v, B0v, out);
}